// Round 1
// baseline (390.323 us; speedup 1.0000x reference)
//
#include <hip/hip_runtime.h>
#include <hip/hip_bf16.h>

// GateAttentionUnit. B=16, N=512, D=1024, E=2048, S=128, F=2E+S=4224.
// CONFIRMED: all 10 inputs fp32, output fp32. Internal compute bf16 MFMA.
//
// Pipeline:
//   K0 rope_table: cos/sin[512][64] fp32 -> d_out scratch
//   K0b cvt uv_w -> bf16 (d_out scratch); K0c cvt o_w -> bf16 (ws)
//   K1 ln:         x -> xn bf16 (d_out scratch)                    [8192 x 1024]
//   K2 gemm256<EpiUV>: silu(xn @ uv_wb^T + uv_b) -> u | vT | base  [8192 x 4224]
//   K3 rope_qk:    q,k = rope(base*gamma+beta) (d_out scratch)     [8192 x 128]
//   K4 gemm_nt<EpiQK>:   km = relu(q@k^T/512 + relpos)^2 (d_out)   [16][512][512]
//   K5 gemm256<EpiAttn>: out2 = u * (km @ vT^T), out2 aliases u    [8192 x 2048]
//   K6 gemm_nt<EpiOut>:  out = out2 @ o_wb^T + o_b + x  (fp32 out) [8192 x 1024]
//
// R7 -> R8: K2/K5 moved to gemm256: 256x256 tile, BK=64, 512 thr (8 waves
// 2Mx4N, 128x64 C each), 128 KiB double-buffered LDS, raw s_barrier +
// counted s_waitcnt vmcnt(8) so next-K-tile global_load_lds stay in flight
// across the barrier (T3/T4), XOR-swizzled LDS (T2), setprio around MFMA
// (T5). N padded 4224->4352 for K2 (pad zero-filled; epilogue skips n>=4224).
// R7 evidence: K2 = 115.6us @ 613 TF, MfmaUtil 26.7%, HBM 17.7% -> structure-
// bound, not memory-bound; m97-structure ceiling. K4/K6 keep 128^2 kernel.
//
// ws (68 MiB; >=69.4 MiB proven available in R5):
//   u [0,32M) (K2->K5; out2 alias K5->K6), vT [32M,64M), o_wb [64M,68M)
// d_out (33.55 MB fp32) dead-interval scratch:
//   xn [0,16M) K1->K2 ; uv_wb [16.78M, 25.69M) 4352 rows (pad zeroed) ;
//   baseb [25.69M, 27.79M) ; cosT/sinT [27.79M, 28.05M) ; then qb [0,2M)
//   kb [2M,4M) K3->K4 ; km [4M,12M) K4->K5. All dead before K6 writes d_out.

typedef __bf16 bf16_t;
typedef __bf16 bf16x4 __attribute__((ext_vector_type(4)));
typedef __bf16 bf16x8 __attribute__((ext_vector_type(8)));
typedef float  f32x4  __attribute__((ext_vector_type(4)));

__device__ __forceinline__ void async16(const void* g, void* l) {
  __builtin_amdgcn_global_load_lds(
      (const __attribute__((address_space(1))) void*)g,
      (__attribute__((address_space(3))) void*)l, 16, 0, 0);
}

// ---------------- sentinel (ws guard diagnostics) ----------------
__global__ __launch_bounds__(256) void fill_const(float* __restrict__ out,
                                                  float val, int n) {
  int i = blockIdx.x * 256 + threadIdx.x;
  if (i < n) out[i] = val;
}

// ---------------- K0: rope sin/cos tables ----------------
__global__ void rope_table(float* __restrict__ cosT, float* __restrict__ sinT) {
  int idx = blockIdx.x * 256 + threadIdx.x;   // 512*64
  int n = idx >> 6, j = idx & 63;
  float invf = (float)pow(10000.0, (double)j * (1.0 / 64.0));
  float angf = (float)n * invf;
  cosT[idx] = (float)cos((double)angf);
  sinT[idx] = (float)sin((double)angf);
}

// ---------------- K0b/K0c: fp32 -> bf16 convert ----------------
__global__ __launch_bounds__(256) void cvt_f32_bf16(const float* __restrict__ in,
                                                    bf16_t* __restrict__ out,
                                                    int n4) {
  int i = blockIdx.x * 256 + threadIdx.x;
  if (i < n4) {
    f32x4 v = ((const f32x4*)in)[i];
    bf16x4 o;
    o[0] = (__bf16)v[0]; o[1] = (__bf16)v[1];
    o[2] = (__bf16)v[2]; o[3] = (__bf16)v[3];
    ((bf16x4*)out)[i] = o;
  }
}

// ---------------- K1: layernorm (fp32 in, bf16 out) ----------------
__global__ __launch_bounds__(256) void ln_kernel(const float* __restrict__ x,
                                                 const float* __restrict__ w,
                                                 const float* __restrict__ b,
                                                 bf16_t* __restrict__ xn) {
  int row = blockIdx.x;
  int tid = threadIdx.x;
  f32x4 v = *(const f32x4*)(x + (size_t)row * 1024 + tid * 4);
  float s = v[0] + v[1] + v[2] + v[3];
  float s2 = v[0]*v[0] + v[1]*v[1] + v[2]*v[2] + v[3]*v[3];
  for (int o = 32; o > 0; o >>= 1) {
    s += __shfl_down(s, o);
    s2 += __shfl_down(s2, o);
  }
  __shared__ float ps[4], ps2[4];
  if ((tid & 63) == 0) { ps[tid >> 6] = s; ps2[tid >> 6] = s2; }
  __syncthreads();
  float st = ps[0] + ps[1] + ps[2] + ps[3];
  float st2 = ps2[0] + ps2[1] + ps2[2] + ps2[3];
  float mean = st * (1.f / 1024.f);
  float var = st2 * (1.f / 1024.f) - mean * mean;
  float inv = 1.f / sqrtf(var + 1e-5f);
  bf16x4 o4;
  for (int i = 0; i < 4; i++) {
    float wn = w[tid * 4 + i], bn = b[tid * 4 + i];
    o4[i] = (__bf16)((v[i] - mean) * inv * wn + bn);
  }
  *(bf16x4*)(xn + (size_t)row * 1024 + tid * 4) = o4;
}

// ---------------- K3: gamma/beta + rope -> q, k ----------------
__global__ __launch_bounds__(128) void rope_qk(const bf16_t* __restrict__ baseb,
                                               const float* __restrict__ gamma,
                                               const float* __restrict__ beta,
                                               const float* __restrict__ cosT,
                                               const float* __restrict__ sinT,
                                               bf16_t* __restrict__ q,
                                               bf16_t* __restrict__ k) {
  int m = blockIdx.x;        // b*512 + n
  int n = m & 511;
  int s = threadIdx.x;       // 0..127
  float base = (float)baseb[(size_t)m * 128 + s];
  __shared__ float t[2][128];
  t[0][s] = base * gamma[s] + beta[s];
  t[1][s] = base * gamma[128 + s] + beta[128 + s];
  __syncthreads();
  int j = s & 63;
  float c = cosT[n * 64 + j], sn = sinT[n * 64 + j];
  for (int h = 0; h < 2; h++) {
    float x1 = t[h][j], x2 = t[h][64 + j];
    float r = (s < 64) ? (x1 * c - x2 * sn) : (x2 * c + x1 * sn);
    bf16_t* dst = h == 0 ? q : k;
    dst[(size_t)m * 128 + s] = (__bf16)r;
  }
}

// ---------------- epilogues (NaN-scrub clamps: never fire on legit data) ----
struct EpiUV {   // + uv_b, silu -> u | vT (transposed) | base
  const float* uv_b;
  bf16_t* u;
  bf16_t* vT;      // [16][2048][512]
  bf16_t* baseb;
  __device__ void operator()(int b, int m, int n, float acc) const {
    if (n >= 4224) return;   // N padded to 4352 for 256-tile
    float xv = acc + uv_b[n];
    float sv = xv / (1.f + __expf(-xv));
    sv = fminf(fmaxf(sv, -100.f), 100.f);
    if (n < 2048) {
      u[(size_t)m * 2048 + n] = (__bf16)sv;
    } else if (n < 4096) {
      int bb = m >> 9, nseq = m & 511;
      vT[((size_t)bb * 2048 + (n - 2048)) * 512 + nseq] = (__bf16)sv;
    } else {
      baseb[(size_t)m * 128 + (n - 4096)] = (__bf16)sv;
    }
  }
};
struct EpiQK {   // clamp(relu(acc/512 + w_rel[511+j-i]))^2 -> km
  const float* w_rel;
  bf16_t* km;
  __device__ void operator()(int b, int i, int j, float acc) const {
    float bias = w_rel[511 + j - i];
    float t = fmaxf(acc * (1.f / 512.f) + bias, 0.f);
    t = fminf(t, 100.f);
    km[((size_t)b * 512 + i) * 512 + j] = (__bf16)(t * t);
  }
};
struct EpiAttn { // clamp(acc * u) -> out2 (out2 aliases u element-exactly)
  const bf16_t* u;
  bf16_t* out2;
  __device__ void operator()(int b, int i, int e, float acc) const {
    size_t m = (size_t)b * 512 + i;
    float uu = (float)u[m * 2048 + e];
    float r = acc * uu;
    r = fminf(fmaxf(r, -1e6f), 1e6f);
    out2[m * 2048 + e] = (__bf16)r;
  }
};
struct EpiOut {  // clamp(acc + o_b + shortcut) -> fp32 out
  const float* o_b;
  const float* x;
  float* out;
  __device__ void operator()(int b, int m, int d, float acc) const {
    long idx = (long)m * 1024 + d;
    float r = acc + o_b[d] + x[idx];
    r = fminf(fmaxf(r, -1e5f), 1e5f);
    out[idx] = r;
  }
};

// ---------------- 128^2 NT GEMM (proven; kept for K4/K6) -------------------
template <typename Epi>
__global__ __launch_bounds__(256, 2)
void gemm_nt(const bf16_t* __restrict__ A, const bf16_t* __restrict__ Bm,
             int lda, int ldb, int K, long sAz, long sBz, Epi epi) {
  __shared__ __align__(16) char smem[32768];
  char* smA = smem;
  char* smB = smem + 16384;
  const int tid = threadIdx.x;
  const int lane = tid & 63;
  const int wid = tid >> 6;
  const int wm = wid & 1, wn = wid >> 1;
  const int quad = lane >> 4, col16 = lane & 15;
  const int srow = lane >> 3;
  const int skc = lane & 7;
  const int bz = blockIdx.z;
  const int tileM = blockIdx.x * 128;
  const int tileN = blockIdx.y * 128;
  const bf16_t* Ab = A + (size_t)bz * sAz;
  const bf16_t* Bb = Bm + (size_t)bz * sBz;

  f32x4 acc[4][4] = {};

  for (int k0 = 0; k0 < K; k0 += 64) {
#pragma unroll
    for (int c4 = 0; c4 < 4; c4++) {
      int ch = c4 * 4 + wid;
      int row = ch * 8 + srow;
      int kc = skc ^ (row & 7);
      async16(Ab + (size_t)(tileM + row) * lda + k0 + kc * 8, smA + ch * 1024);
      async16(Bb + (size_t)(tileN + row) * ldb + k0 + kc * 8, smB + ch * 1024);
    }
    __syncthreads();
#pragma unroll
    for (int kk = 0; kk < 2; kk++) {
      bf16x8 af[4], bfr[4];
      int jj = kk * 4 + quad;
#pragma unroll
      for (int t = 0; t < 4; t++) {
        int ml = wm * 64 + t * 16 + col16;
        int nl = wn * 64 + t * 16 + col16;
        af[t] = *(const bf16x8*)(smA + (size_t)ml * 128 + ((jj ^ (ml & 7)) * 16));
        bfr[t] = *(const bf16x8*)(smB + (size_t)nl * 128 + ((jj ^ (nl & 7)) * 16));
      }
#pragma unroll
      for (int mt = 0; mt < 4; mt++)
#pragma unroll
        for (int nt = 0; nt < 4; nt++)
          acc[mt][nt] = __builtin_amdgcn_mfma_f32_16x16x32_bf16(af[mt], bfr[nt], acc[mt][nt], 0, 0, 0);
    }
    __syncthreads();
  }

#pragma unroll
  for (int mt = 0; mt < 4; mt++) {
    int gm = tileM + wm * 64 + mt * 16 + quad * 4;
#pragma unroll
    for (int nt = 0; nt < 4; nt++) {
      int gn = tileN + wn * 64 + nt * 16 + col16;
#pragma unroll
      for (int r = 0; r < 4; r++) epi(bz, gm + r, gn, acc[mt][nt][r]);
    }
  }
}

// ---------------- 256^2 deep-pipelined NT GEMM (K2/K5) ---------------------
// 512 thr = 8 waves (2M x 4N), per-wave C = 128x64 (acc[8][4] f32x4 = 128 r).
// LDS 128 KiB: buf0 {A[256][64] | B[256][64]}, buf1 same. XOR-swizzled rows
// (slot c of row r holds k-chunk c^(r&7); staged via pre-swizzled global src).
// Schedule: prologue stages KT0,KT1; iter t computes buf(t&1) in 4 quadrant
// phases (24 ds_read_b128/wave, B frags held, A reloaded once), then:
//   s_barrier (all reads of buf done) ; stage KT(t+2) into buf ;
//   s_waitcnt vmcnt(8)  [KT(t+1) resident; KT(t+2)'s 8 loads stay in flight]
//   s_barrier (all waves' loads confirmed -- vmcnt is per-wave).
// NO __syncthreads in the loop (it would drain vmcnt(0) and kill the
// pipeline). Empty "memory" asm fences pin ds_reads/stages vs raw barriers.
template <typename Epi>
__global__ __launch_bounds__(512, 2)
void gemm256(const bf16_t* __restrict__ A, const bf16_t* __restrict__ Bm,
             int lda, int ldb, int K, long sAz, long sBz, Epi epi) {
  __shared__ __align__(16) char smem[131072];
  const int tid = threadIdx.x;
  const int lane = tid & 63;
  const int wid = tid >> 6;       // 0..7
  const int wr = wid & 1;         // M half (128 rows)
  const int wc = wid >> 1;        // N quarter (64 cols)
  const int quad = lane >> 4, col16 = lane & 15;
  const int bz = blockIdx.z;
  const int tileM = blockIdx.x * 256;
  const int tileN = blockIdx.y * 256;
  const bf16_t* Ab = A + (size_t)bz * sAz;
  const bf16_t* Bb = Bm + (size_t)bz * sBz;
  const int NT = K >> 6;          // K-tiles of 64 (NT >= 2 required)

  f32x4 acc[8][4] = {};

  auto stage = [&](int kt, int buf) {   // one K-tile: A 32KB + B 32KB, 8 loads
    char* dA = (char*)smem + buf * 65536;
    char* dB = dA + 32768;
    const int k0 = kt << 6;
#pragma unroll
    for (int i = 0; i < 4; i++) {
      int li = i * 512 + tid;           // 16B chunk index, 2048 per matrix
      int r = li >> 3;                  // row 0..255
      int kc = (li & 7) ^ (r & 7);      // fetch chunk kc into LDS slot li&7
      async16(Ab + (size_t)(tileM + r) * lda + k0 + kc * 8, dA + li * 16);
      async16(Bb + (size_t)(tileN + r) * ldb + k0 + kc * 8, dB + li * 16);
    }
  };

  stage(0, 0);
  stage(1, 1);
  asm volatile("s_waitcnt vmcnt(8)" ::: "memory");   // KT0 resident (mine)
  __builtin_amdgcn_s_barrier();                       // KT0 resident (all)
  asm volatile("" ::: "memory");

  for (int t = 0; t < NT; t++) {
    const char* sA = (const char*)smem + (t & 1) * 65536;
    const char* sB = sA + 32768;

    bf16x8 a[4][2], b0[2][2], b1[2][2];

#define RD_A4(mbase)                                                          \
  {                                                                           \
    _Pragma("unroll") for (int mt = 0; mt < 4; mt++)                          \
        _Pragma("unroll") for (int kk = 0; kk < 2; kk++) {                    \
      int ml = wr * 128 + ((mbase) + mt) * 16 + col16;                        \
      int jj = kk * 4 + quad;                                                 \
      a[mt][kk] =                                                             \
          *(const bf16x8*)(sA + (size_t)ml * 128 + ((jj ^ (ml & 7)) << 4));   \
    }                                                                         \
  }
#define RD_B2(b, nbase)                                                       \
  {                                                                           \
    _Pragma("unroll") for (int nt = 0; nt < 2; nt++)                          \
        _Pragma("unroll") for (int kk = 0; kk < 2; kk++) {                    \
      int nl = wc * 64 + ((nbase) + nt) * 16 + col16;                         \
      int jj = kk * 4 + quad;                                                 \
      b[nt][kk] =                                                             \
          *(const bf16x8*)(sB + (size_t)nl * 128 + ((jj ^ (nl & 7)) << 4));   \
    }                                                                         \
  }
#define MM8(mo, no, b)                                                        \
  {                                                                           \
    __builtin_amdgcn_s_setprio(1);                                            \
    _Pragma("unroll") for (int mt = 0; mt < 4; mt++)                          \
        _Pragma("unroll") for (int nt = 0; nt < 2; nt++)                      \
            _Pragma("unroll") for (int kk = 0; kk < 2; kk++) {                \
      acc[(mo) + mt][(no) + nt] = __builtin_amdgcn_mfma_f32_16x16x32_bf16(    \
          a[mt][kk], b[nt][kk], acc[(mo) + mt][(no) + nt], 0, 0, 0);          \
    }                                                                         \
    __builtin_amdgcn_s_setprio(0);                                            \
  }

    RD_B2(b0, 0);        // phase 0: B n0-1 + A m0-3
    RD_A4(0);
    MM8(0, 0, b0);
    RD_B2(b1, 2);        // phase 1: B n2-3 (A m0-3 held)
    MM8(0, 2, b1);
    RD_A4(4);            // phase 2: A m4-7 (b1 held)
    MM8(4, 2, b1);
    MM8(4, 0, b0);       // phase 3: zero new reads (b0 held)

#undef RD_A4
#undef RD_B2
#undef MM8

    if (t == NT - 1) break;
    asm volatile("" ::: "memory");
    __builtin_amdgcn_s_barrier();          // all waves done reading buf (t&1)
    if (t + 2 < NT) {
      stage(t + 2, t & 1);                 // overwrite just-freed buffer
      asm volatile("s_waitcnt vmcnt(8)" ::: "memory");  // KT(t+1) done (mine)
    } else {
      asm volatile("s_waitcnt vmcnt(0)" ::: "memory");
    }
    __builtin_amdgcn_s_barrier();          // KT(t+1) resident for all waves
    asm volatile("" ::: "memory");
  }

#pragma unroll
  for (int mt = 0; mt < 8; mt++) {
    int gm = tileM + wr * 128 + mt * 16 + quad * 4;
#pragma unroll
    for (int nt = 0; nt < 4; nt++) {
      int gn = tileN + wc * 64 + nt * 16 + col16;
#pragma unroll
      for (int r = 0; r < 4; r++) epi(bz, gm + r, gn, acc[mt][nt][r]);
    }
  }
}

extern "C" void kernel_launch(void* const* d_in, const int* in_sizes, int n_in,
                              void* d_out, int out_size, void* d_ws, size_t ws_size,
                              hipStream_t stream) {
  const float* x = (const float*)d_in[0];
  const float* ln_w = (const float*)d_in[1];
  const float* ln_b = (const float*)d_in[2];
  const float* uv_w = (const float*)d_in[3];
  const float* uv_b = (const float*)d_in[4];
  const float* gamma = (const float*)d_in[5];
  const float* beta = (const float*)d_in[6];
  const float* o_w = (const float*)d_in[7];
  const float* o_b = (const float*)d_in[8];
  const float* w_rel = (const float*)d_in[9];
  float* out = (float*)d_out;

  const int NOUT = 8388608;
  const size_t WS_NEEDED = 71303168;   // 68 MiB (>=69.4 MiB proven in R5)
  if (ws_size < WS_NEEDED) {
    float wsMiB = (float)(ws_size >> 20);
    fill_const<<<dim3(32768), dim3(256), 0, stream>>>(out, 1000.f + wsMiB, NOUT);
    return;
  }

  // ws: u [0,32M) (out2 alias), vT [32M,64M), o_wb [64M,68M)
  char* ws = (char*)d_ws;
  bf16_t* u = (bf16_t*)(ws + 0);
  bf16_t* out2 = u;
  bf16_t* vT = (bf16_t*)(ws + 33554432);
  bf16_t* o_wb = (bf16_t*)(ws + 67108864);
  // d_out dead-interval scratch (33.55 MB fp32 region):
  char* ob = (char*)d_out;
  bf16_t* xn = (bf16_t*)ob;                       // [0, 16,777,216)
  bf16_t* uv_wb = (bf16_t*)(ob + 16777216);       // 4352 rows: [16.78M, 25.69M)
  bf16_t* baseb = (bf16_t*)(ob + 25690112);       // [25,690,112, 27,787,264)
  float* cosT = (float*)(ob + 27787264);          // [27,787,264, 27,918,336)
  float* sinT = (float*)(ob + 27918336);          // [27,918,336, 28,049,408)
  bf16_t* qb = (bf16_t*)ob;                       // [0, 2M)   K3->K4
  bf16_t* kb = (bf16_t*)(ob + 2097152);           // [2M, 4M)  K3->K4
  bf16_t* km = (bf16_t*)(ob + 4194304);           // [4M, 12M) K4->K5

  rope_table<<<dim3(128), dim3(256), 0, stream>>>(cosT, sinT);
  cvt_f32_bf16<<<dim3(4224), dim3(256), 0, stream>>>(uv_w, uv_wb, 1081344);
  cvt_f32_bf16<<<dim3(2048), dim3(256), 0, stream>>>(o_w, o_wb, 524288);
  // zero the N-pad rows 4224..4351 of uv_wb (256 KiB = 65536 floats)
  fill_const<<<dim3(256), dim3(256), 0, stream>>>(
      (float*)(ob + 16777216 + 8650752), 0.f, 65536);
  ln_kernel<<<dim3(8192), dim3(256), 0, stream>>>(x, ln_w, ln_b, xn);
  // K2: silu(xn @ uv_wb^T + uv_b) -> u | vT | base: M=8192, N=4352(pad), K=1024
  gemm256<<<dim3(32, 17, 1), dim3(512), 0, stream>>>(
      xn, uv_wb, 1024, 1024, 1024, 0L, 0L, EpiUV{uv_b, u, vT, baseb});
  rope_qk<<<dim3(8192), dim3(128), 0, stream>>>(baseb, gamma, beta, cosT, sinT, qb, kb);
  // K4: km = relu(q@k^T/512 + bias)^2: per batch M=N=512, K=128
  gemm_nt<<<dim3(4, 4, 16), dim3(256), 0, stream>>>(
      qb, kb, 128, 128, 128, (long)512 * 128, (long)512 * 128, EpiQK{w_rel, km});
  // K5: out2 = u * (km @ v): per batch M=512, N=2048, K=512
  gemm256<<<dim3(2, 8, 16), dim3(512), 0, stream>>>(
      km, vT, 512, 512, 512, (long)512 * 512, (long)2048 * 512, EpiAttn{u, out2});
  // K6: out = out2 @ o_wb^T + o_b + x: M=8192, N=1024, K=2048
  gemm_nt<<<dim3(64, 8, 1), dim3(256), 0, stream>>>(
      out2, o_wb, 2048, 2048, 2048, 0L, 0L, EpiOut{o_b, x, out});
}